// Round 7
// baseline (301.917 us; speedup 1.0000x reference)
//
#include <hip/hip_runtime.h>
#include <hip/hip_bf16.h>

typedef __attribute__((ext_vector_type(8))) short short8;
typedef __attribute__((ext_vector_type(4))) float f32x4;

#define MFMA16(a,b,c) __builtin_amdgcn_mfma_f32_16x16x32_bf16((a),(b),(c),0,0,0)

constexpr int BHn = 32;     // B*NH
constexpr int Tn  = 2048;
constexpr int Nn  = 512;
constexpr int Dn  = 128;
constexpr int CHn = 64;     // chunk length
constexpr int NCH = Tn / CHn;

static __device__ __forceinline__ unsigned short f2b(float x){
  __hip_bfloat16 h = __float2bfloat16(x);
  return *reinterpret_cast<unsigned short*>(&h);
}

// ---------------- Kernel 1: RoPE(Q) -> bf16, shared sincos across bh ----------------
__global__ __launch_bounds__(256) void rope_k(const float* __restrict__ Q,
                                              const float* __restrict__ freqs,
                                              unsigned short* __restrict__ QR){
  int gid = blockIdx.x * 256 + threadIdx.x;   // 2048 blocks * 256 = T * 256
  int np  = gid & 255;                        // pair index n in [0,256)
  int t   = gid >> 8;                         // [0,2048)
  float tf = (float)t;
  float f1 = freqs[np], f2 = freqs[np + 256];
  float s1, c1, s2, c2;
  sincosf(tf * f1, &s1, &c1);
  sincosf(tf * f2, &s2, &c2);
  size_t off = (size_t)t * Nn + np;
  for (int bh = 0; bh < BHn; ++bh){
    size_t base = (size_t)bh * Tn * Nn + off;
    float q1 = Q[base], q2 = Q[base + 256];
    QR[base]       = f2b(q1 * c1 - q2 * s1);   // n < 256: q*cos - q[n+256]*sin
    QR[base + 256] = f2b(q2 * c2 + q1 * s2);   // n >=256: q*cos + q[n-256]*sin
  }
}

// ---------------- LDS fragment loader (swizzled, for SbTs/VTs/Ps) ----------------
// standard swizzle: col ^= (row&7)<<3 (16B granules)
__device__ __forceinline__ short8 ldfrag(const unsigned short* buf, int rowbase, int k0, int ld, int lane){
  int row = rowbase + (lane & 15);
  int col = (k0 + ((lane >> 4) << 3)) ^ ((row & 7) << 3);
  return *reinterpret_cast<const short8*>(buf + row * ld + col);
}

// ---------------- global A-frag loader: R rows direct from QR (L2-resident chunk) ----
// A-frag for tile row base `rowbase`, k-slice k0: lane reads QR[t0+rowbase+(lane&15)][k0+(lane>>4)*8 ..+8]
__device__ __forceinline__ short8 gfrag(const unsigned short* Qc, int rowbase, int k0, int lane){
  return *reinterpret_cast<const short8*>(
      Qc + (size_t)(rowbase + (lane & 15)) * Nn + k0 + ((lane >> 4) << 3));
}

// ---------------- Kernel 2: chunked linear-attention scan, 8 waves, 2 barriers/chunk ----
// No R staging at all: compute waves read A-frags direct from global QR (L2-hot 64KB chunk,
// shared across the 8 dch blocks of this bh on one XCD); state waves gather their B-frags
// direct from global QR (u16 column gather on the VMEM pipe). LDS holds only SbTs/VTs/Ps.
__global__ __launch_bounds__(512, 1) void lattn_main(
    const unsigned short* __restrict__ QR,   // bf16 (BH,T,N)
    const float* __restrict__ V,             // (BH,T,D)
    const float* __restrict__ S_prev,        // (BH,N,D)
    const float* __restrict__ gammap,
    float* __restrict__ Out,                 // (BH,T,D)
    float* __restrict__ Sfin)                // (BH,N,D)
{
  __shared__ __align__(16) unsigned short SbTs[16 * 512];  // bf16(S_start)^T [d][n] (16 KB)
  __shared__ __align__(16) unsigned short VTs[2][16 * 64]; // Vt^T [d][dt] double-buffered (4 KB)
  __shared__ __align__(16) unsigned short Ps [64 * 64];    // P~ [i][j] (8 KB)
  __shared__ float gpow[65], gpinv[65];

  const int tid  = threadIdx.x;
  const int w    = tid >> 6;
  const int lane = tid & 63;
  const int bh   = blockIdx.x & 31;   // same bh -> same XCD (blockIdx%8 == bh%8)
  const int dch  = blockIdx.x >> 5;   // 8 d-slices of 16
  const int d0   = dch * 16;
  const float g  = gammap[0];

  const unsigned short* QRbh = QR + (size_t)bh * Tn * Nn;
  const float* Vbh = V + (size_t)bh * Tn * Dn;

  // ---- prologue ----
  if (tid < 65){
    gpow[tid]  = powf(g,  (float)tid);
    gpinv[tid] = powf(g, -(float)tid);
  }
  #pragma unroll
  for (int i = tid; i < 64 * 64; i += 512) Ps[i] = 0;  // strictly-upper tiles stay 0 forever

  f32x4 st[8];  // waves 4-7: state S^T[d][n], 8 n-tiles each (D-frag: col=n=lane&15, row=d=4*(lane>>4)+r)
  if (w >= 4){
    int r0 = (w - 4) * 8;
    #pragma unroll
    for (int j = 0; j < 8; ++j){
      int n = (r0 + j) * 16 + (lane & 15);
      const float* sp = S_prev + (size_t)bh * Nn * Dn + (size_t)n * Dn + d0 + ((lane >> 4) << 2);
      st[j] = *reinterpret_cast<const f32x4*>(sp);
    }
  }
  __syncthreads();   // gpow/gpinv ready
  const float g64 = gpow[64];

  // ---- stage chunk 0 (VTs + SbTs only) ----
  {
    int dtv = tid >> 3, dp = (tid & 7) << 1;
    const float* vp = Vbh + (size_t)dtv * Dn + d0 + dp;
    float sc = gpinv[dtv];
    VTs[0][ dp      * 64 + (dtv ^ (( dp      & 7) << 3))] = f2b(vp[0] * sc);
    VTs[0][(dp + 1) * 64 + (dtv ^ (((dp + 1) & 7) << 3))] = f2b(vp[1] * sc);
    if (w >= 4){
      int r0 = (w - 4) * 8;
      #pragma unroll
      for (int j = 0; j < 8; ++j){
        int n  = (r0 + j) * 16 + (lane & 15);
        int dl = (lane >> 4) << 2;
        #pragma unroll
        for (int r = 0; r < 4; ++r){
          int d = dl + r;
          SbTs[d * 512 + (n ^ ((d & 7) << 3))] = f2b(st[j][r]);
        }
      }
    }
  }
  __syncthreads();

  for (int c = 0; c < NCH; ++c){
    const int t0 = c * CHn;
    const int vb = c & 1;
    const bool pf = (c + 1 < NCH);
    const unsigned short* Qc = QRbh + (size_t)t0 * Nn;   // this chunk's R (L2-hot)

    // ---- V prefetch for chunk c+1 (VTs staged in Ph2) ----
    float va0 = 0.f, va1 = 0.f;
    const int dtv_ = tid >> 3;
    if (pf){
      const float* vp = Vbh + (size_t)(t0 + CHn + dtv_) * Dn + d0 + ((tid & 7) << 1);
      va0 = vp[0]; va1 = vp[1];
    }

    // ================= Ph1 =================
    f32x4 oacc = {0.f, 0.f, 0.f, 0.f};
    if (w < 4){
      // P~ lower/diag tiles + OutT[d][i] += SbT-frag x R-frag, fused k-loop; R from global
      f32x4 p0 = {0.f,0.f,0.f,0.f}, p1 = p0, p2 = p0;
      #pragma unroll
      for (int kb = 0; kb < 16; ++kb){
        int k0 = kb * 32;
        short8 fs = ldfrag(SbTs, 0, k0, 512, lane);
        if (w == 0){
          short8 f0 = gfrag(Qc,  0, k0, lane);
          short8 f1 = gfrag(Qc, 16, k0, lane);
          p0   = MFMA16(f0, f0, p0);      // (0,0)
          p1   = MFMA16(f1, f0, p1);      // (1,0)
          p2   = MFMA16(f1, f1, p2);      // (1,1)
          oacc = MFMA16(fs, f0, oacc);    // i-tile 0
        } else if (w == 1){
          short8 f0 = gfrag(Qc,  0, k0, lane);
          short8 f1 = gfrag(Qc, 16, k0, lane);
          short8 f2 = gfrag(Qc, 32, k0, lane);
          p0   = MFMA16(f2, f0, p0);      // (2,0)
          p1   = MFMA16(f2, f1, p1);      // (2,1)
          p2   = MFMA16(f2, f2, p2);      // (2,2)
          oacc = MFMA16(fs, f2, oacc);    // i-tile 2
        } else if (w == 2){
          short8 f0 = gfrag(Qc,  0, k0, lane);
          short8 f1 = gfrag(Qc, 16, k0, lane);
          short8 f3 = gfrag(Qc, 48, k0, lane);
          p0   = MFMA16(f3, f0, p0);      // (3,0)
          p1   = MFMA16(f3, f1, p1);      // (3,1)
          oacc = MFMA16(fs, f3, oacc);    // i-tile 3
        } else {
          short8 f1 = gfrag(Qc, 16, k0, lane);
          short8 f2 = gfrag(Qc, 32, k0, lane);
          short8 f3 = gfrag(Qc, 48, k0, lane);
          p0   = MFMA16(f3, f2, p0);      // (3,2)
          p1   = MFMA16(f3, f3, p1);      // (3,3)
          oacc = MFMA16(fs, f1, oacc);    // i-tile 1
        }
      }
      // epilogue: P~[i][j] = (j<i) ? gamma^i * acc : 0   (C-frag: col=j=lane&15, row=i=4*(lane>>4)+r)
      int tI[3], tJ[3], nt;
      if      (w == 0){ tI[0]=0; tJ[0]=0; tI[1]=1; tJ[1]=0; tI[2]=1; tJ[2]=1; nt = 3; }
      else if (w == 1){ tI[0]=2; tJ[0]=0; tI[1]=2; tJ[1]=1; tI[2]=2; tJ[2]=2; nt = 3; }
      else if (w == 2){ tI[0]=3; tJ[0]=0; tI[1]=3; tJ[1]=1; tI[2]=0; tJ[2]=0; nt = 2; }
      else            { tI[0]=3; tJ[0]=2; tI[1]=3; tJ[1]=3; tI[2]=0; tJ[2]=0; nt = 2; }
      f32x4 pacc[3] = {p0, p1, p2};
      for (int q = 0; q < nt; ++q){
        int j  = tJ[q] * 16 + (lane & 15);
        int i0 = tI[q] * 16 + ((lane >> 4) << 2);
        #pragma unroll
        for (int r = 0; r < 4; ++r){
          int i = i0 + r;
          float v = (j < i) ? pacc[q][r] * gpow[i] : 0.f;
          Ps[i * 64 + (j ^ ((i & 7) << 3))] = f2b(v);
        }
      }
    } else {
      // state update S^T += VTs(A) x R-column-gather-from-global(B), then *gamma^64
      int r0 = (w - 4) * 8;
      #pragma unroll
      for (int ks = 0; ks < 2; ++ks){
        short8 av = ldfrag(VTs[vb], 0, ks * 32, 64, lane);
        #pragma unroll
        for (int j = 0; j < 8; ++j){
          int n = (r0 + j) * 16 + (lane & 15);
          const unsigned short* col = Qc + (size_t)(ks * 32 + ((lane >> 4) << 3)) * Nn + n;
          short8 bn;
          #pragma unroll
          for (int e = 0; e < 8; ++e) bn[e] = (short)col[(size_t)e * Nn];
          st[j] = MFMA16(av, bn, st[j]);
        }
      }
      #pragma unroll
      for (int j = 0; j < 8; ++j)
        #pragma unroll
        for (int r = 0; r < 4; ++r) st[j][r] *= g64;
    }
    __syncthreads();

    // ================= Ph2: out store + SbT/VTs staging for c+1 =================
    if (w >= 4){
      // SbT for chunk c+1 (st already updated+scaled = S_start(c+1))
      int r0 = (w - 4) * 8;
      #pragma unroll
      for (int j = 0; j < 8; ++j){
        int n  = (r0 + j) * 16 + (lane & 15);
        int dl = (lane >> 4) << 2;
        #pragma unroll
        for (int r = 0; r < 4; ++r){
          int d = dl + r;
          SbTs[d * 512 + (n ^ ((d & 7) << 3))] = f2b(st[j][r]);
        }
      }
    } else {
      // out = gamma^i * inter + intra
      const int itl = (w == 0) ? 0 : (w == 1) ? 2 : (w == 2) ? 3 : 1;
      float gi = gpow[itl * 16 + (lane & 15)];   // inter term scale gamma^i (col = i)
      #pragma unroll
      for (int r = 0; r < 4; ++r) oacc[r] *= gi;
      #pragma unroll
      for (int ks = 0; ks < 2; ++ks){
        short8 av = ldfrag(VTs[vb], 0, ks * 32, 64, lane);
        short8 bp = ldfrag(Ps, itl * 16, ks * 32, 64, lane);
        oacc = MFMA16(av, bp, oacc);   // OutT[d][i] += sum_j VT[d][j] * P~[i][j]
      }
      int ti = t0 + itl * 16 + (lane & 15);
      float* op = Out + (size_t)bh * Tn * Dn + (size_t)ti * Dn + d0 + ((lane >> 4) << 2);
      *reinterpret_cast<f32x4*>(op) = oacc;
    }
    if (pf){
      int dp = (tid & 7) << 1;
      float sc = gpinv[dtv_];
      VTs[vb ^ 1][ dp      * 64 + (dtv_ ^ (( dp      & 7) << 3))] = f2b(va0 * sc);
      VTs[vb ^ 1][(dp + 1) * 64 + (dtv_ ^ (((dp + 1) & 7) << 3))] = f2b(va1 * sc);
    }
    __syncthreads();
  }

  // ---- epilogue: final state ----
  if (w >= 4){
    int r0 = (w - 4) * 8;
    #pragma unroll
    for (int j = 0; j < 8; ++j){
      int n = (r0 + j) * 16 + (lane & 15);
      float* sp = Sfin + (size_t)bh * Nn * Dn + (size_t)n * Dn + d0 + ((lane >> 4) << 2);
      *reinterpret_cast<f32x4*>(sp) = st[j];
    }
  }
}

extern "C" void kernel_launch(void* const* d_in, const int* in_sizes, int n_in,
                              void* d_out, int out_size, void* d_ws, size_t ws_size,
                              hipStream_t stream){
  const float* Q      = (const float*)d_in[0];
  const float* V      = (const float*)d_in[1];
  const float* S_prev = (const float*)d_in[2];
  const float* freqs  = (const float*)d_in[3];
  const float* gamma  = (const float*)d_in[4];
  float* Out  = (float*)d_out;
  float* Sfin = Out + (size_t)BHn * Tn * Dn;
  unsigned short* QR = (unsigned short*)d_ws;   // 64 MB bf16 scratch

  rope_k<<<2048, 256, 0, stream>>>(Q, freqs, QR);
  lattn_main<<<256, 512, 0, stream>>>(QR, V, S_prev, gamma, Out, Sfin);
}

// Round 8
// 201.961 us; speedup vs baseline: 1.4949x; 1.4949x over previous
//
#include <hip/hip_runtime.h>
#include <hip/hip_bf16.h>

typedef __attribute__((ext_vector_type(8))) short short8;
typedef __attribute__((ext_vector_type(4))) float f32x4;

#define MFMA16(a,b,c) __builtin_amdgcn_mfma_f32_16x16x32_bf16((a),(b),(c),0,0,0)

constexpr int BHn = 32;     // B*NH
constexpr int Tn  = 2048;
constexpr int Nn  = 512;
constexpr int Dn  = 128;
constexpr int CHn = 64;     // chunk length
constexpr int NCH = Tn / CHn;

static __device__ __forceinline__ unsigned short f2b(float x){
  __hip_bfloat16 h = __float2bfloat16(x);
  return *reinterpret_cast<unsigned short*>(&h);
}

// ---------------- Kernel 1: RoPE(Q) -> bf16, shared sincos across bh ----------------
__global__ __launch_bounds__(256) void rope_k(const float* __restrict__ Q,
                                              const float* __restrict__ freqs,
                                              unsigned short* __restrict__ QR){
  int gid = blockIdx.x * 256 + threadIdx.x;   // 2048 blocks * 256 = T * 256
  int np  = gid & 255;                        // pair index n in [0,256)
  int t   = gid >> 8;                         // [0,2048)
  float tf = (float)t;
  float f1 = freqs[np], f2 = freqs[np + 256];
  float s1, c1, s2, c2;
  sincosf(tf * f1, &s1, &c1);
  sincosf(tf * f2, &s2, &c2);
  size_t off = (size_t)t * Nn + np;
  for (int bh = 0; bh < BHn; ++bh){
    size_t base = (size_t)bh * Tn * Nn + off;
    float q1 = Q[base], q2 = Q[base + 256];
    QR[base]       = f2b(q1 * c1 - q2 * s1);   // n < 256: q*cos - q[n+256]*sin
    QR[base + 256] = f2b(q2 * c2 + q1 * s2);   // n >=256: q*cos + q[n-256]*sin
  }
}

// ---------------- LDS fragment loaders (swizzled) ----------------
// standard swizzle: col ^= (row&7)<<3 (16B granules)
__device__ __forceinline__ short8 ldfrag(const unsigned short* buf, int rowbase, int k0, int ld, int lane){
  int row = rowbase + (lane & 15);
  int col = (k0 + ((lane >> 4) << 3)) ^ ((row & 7) << 3);
  return *reinterpret_cast<const short8*>(buf + row * ld + col);
}

// ---------------- staging writer: one even row-pair of R into Rs (b128 only) ----------
__device__ __forceinline__ void stage_Rs(unsigned short* Rs, uint4 a, uint4 b, int dt, int n0){
  *reinterpret_cast<uint4*>(&Rs[ dt      * 512 + (n0 ^ (( dt      & 7) << 3))]) = a;
  *reinterpret_cast<uint4*>(&Rs[(dt + 1) * 512 + (n0 ^ (((dt + 1) & 7) << 3))]) = b;
}

// ---------------- Kernel 2: chunked linear-attention scan, 8 waves, 2 barriers/chunk ----
// Waves 0-3: compute (P~ tiles + one oacc i-tile each) — A/B frags from LDS Rs (dense stream).
// Waves 4-7: state, 8 n-tiles each — B-frag column-gather DIRECT FROM GLOBAL QR (L2-hot
// chunk; scattered u16 traffic rides the idle VMEM pipe instead of the saturated DS pipe).
__global__ __launch_bounds__(512, 1) void lattn_main(
    const unsigned short* __restrict__ QR,   // bf16 (BH,T,N)
    const float* __restrict__ V,             // (BH,T,D)
    const float* __restrict__ S_prev,        // (BH,N,D)
    const float* __restrict__ gammap,
    float* __restrict__ Out,                 // (BH,T,D)
    float* __restrict__ Sfin)                // (BH,N,D)
{
  __shared__ __align__(16) unsigned short Rs [64 * 512];   // R row-major [dt][n] (64 KB)
  __shared__ __align__(16) unsigned short SbTs[16 * 512];  // bf16(S_start)^T [d][n] (16 KB)
  __shared__ __align__(16) unsigned short VTs[2][16 * 64]; // Vt^T [d][dt] double-buffered
  __shared__ __align__(16) unsigned short Ps [64 * 64];    // P~ [i][j]
  __shared__ float gpow[65], gpinv[65];

  const int tid  = threadIdx.x;
  const int w    = tid >> 6;
  const int lane = tid & 63;
  const int bh   = blockIdx.x & 31;   // same bh -> same XCD (blockIdx%8 == bh%8)
  const int dch  = blockIdx.x >> 5;   // 8 d-slices of 16
  const int d0   = dch * 16;
  const float g  = gammap[0];

  const unsigned short* QRbh = QR + (size_t)bh * Tn * Nn;
  const float* Vbh = V + (size_t)bh * Tn * Dn;

  // ---- prologue ----
  if (tid < 65){
    gpow[tid]  = powf(g,  (float)tid);
    gpinv[tid] = powf(g, -(float)tid);
  }
  #pragma unroll
  for (int i = tid; i < 64 * 64; i += 512) Ps[i] = 0;  // strictly-upper tiles stay 0 forever

  f32x4 st[8];  // waves 4-7: state S^T[d][n], 8 n-tiles each (D-frag: col=n=lane&15, row=d=4*(lane>>4)+r)
  if (w >= 4){
    int r0 = (w - 4) * 8;
    #pragma unroll
    for (int j = 0; j < 8; ++j){
      int n = (r0 + j) * 16 + (lane & 15);
      const float* sp = S_prev + (size_t)bh * Nn * Dn + (size_t)n * Dn + d0 + ((lane >> 4) << 2);
      st[j] = *reinterpret_cast<const f32x4*>(sp);
    }
  }
  __syncthreads();   // gpow/gpinv ready
  const float g64 = gpow[64];

  // ---- stage chunk 0 ----
  {
    #pragma unroll
    for (int i = 0; i < 4; ++i){
      int p  = tid + i * 512;
      int dt = (p >> 6) << 1;
      int n0 = (p & 63) << 3;
      const unsigned short* src = QRbh + (size_t)dt * Nn + n0;
      uint4 a = *reinterpret_cast<const uint4*>(src);
      uint4 b = *reinterpret_cast<const uint4*>(src + Nn);
      stage_Rs(Rs, a, b, dt, n0);
    }
    {
      int dtv = tid >> 3, dp = (tid & 7) << 1;
      const float* vp = Vbh + (size_t)dtv * Dn + d0 + dp;
      float sc = gpinv[dtv];
      VTs[0][ dp      * 64 + (dtv ^ (( dp      & 7) << 3))] = f2b(vp[0] * sc);
      VTs[0][(dp + 1) * 64 + (dtv ^ (((dp + 1) & 7) << 3))] = f2b(vp[1] * sc);
    }
    if (w >= 4){
      int r0 = (w - 4) * 8;
      #pragma unroll
      for (int j = 0; j < 8; ++j){
        int n  = (r0 + j) * 16 + (lane & 15);
        int dl = (lane >> 4) << 2;
        #pragma unroll
        for (int r = 0; r < 4; ++r){
          int d = dl + r;
          SbTs[d * 512 + (n ^ ((d & 7) << 3))] = f2b(st[j][r]);
        }
      }
    }
  }
  __syncthreads();   // chunk 0 resident

  for (int c = 0; c < NCH; ++c){
    const int t0 = c * CHn;
    const int vb = c & 1;
    const bool pf = (c + 1 < NCH);
    const unsigned short* Qc = QRbh + (size_t)t0 * Nn;   // this chunk's R (L2-hot)

    // ---- prefetch chunk c+1 into registers (latency hides under Ph1 compute) ----
    uint4 ra[4], rb[4];
    float va0 = 0.f, va1 = 0.f;
    const int n0_  = (tid & 63) << 3;
    const int dtv_ = tid >> 3;
    if (pf){
      const unsigned short* QRc = QRbh + (size_t)(t0 + CHn) * Nn;
      #pragma unroll
      for (int i = 0; i < 4; ++i){
        int dt = (((tid >> 6) + 8 * i) << 1);
        const unsigned short* src = QRc + (size_t)dt * Nn + n0_;
        ra[i] = *reinterpret_cast<const uint4*>(src);
        rb[i] = *reinterpret_cast<const uint4*>(src + Nn);
      }
      const float* vp = Vbh + (size_t)(t0 + CHn + dtv_) * Dn + d0 + ((tid & 7) << 1);
      va0 = vp[0]; va1 = vp[1];
    }

    // ================= Ph1 =================
    f32x4 oacc = {0.f, 0.f, 0.f, 0.f};
    if (w < 4){
      // G1: P~ lower/diag tiles + G2': OutT[d][i] += SbT-frag x R-colfrag (fused k-loop)
      f32x4 p0 = {0.f,0.f,0.f,0.f}, p1 = p0, p2 = p0;
      for (int kb = 0; kb < 16; ++kb){
        int k0 = kb * 32;
        short8 fs = ldfrag(SbTs, 0, k0, 512, lane);
        if (w == 0){
          short8 f0 = ldfrag(Rs,  0, k0, 512, lane);
          short8 f1 = ldfrag(Rs, 16, k0, 512, lane);
          p0   = MFMA16(f0, f0, p0);      // (0,0)
          p1   = MFMA16(f1, f0, p1);      // (1,0)
          p2   = MFMA16(f1, f1, p2);      // (1,1)
          oacc = MFMA16(fs, f0, oacc);    // i-tile 0
        } else if (w == 1){
          short8 f0 = ldfrag(Rs,  0, k0, 512, lane);
          short8 f1 = ldfrag(Rs, 16, k0, 512, lane);
          short8 f2 = ldfrag(Rs, 32, k0, 512, lane);
          p0   = MFMA16(f2, f0, p0);      // (2,0)
          p1   = MFMA16(f2, f1, p1);      // (2,1)
          p2   = MFMA16(f2, f2, p2);      // (2,2)
          oacc = MFMA16(fs, f2, oacc);    // i-tile 2
        } else if (w == 2){
          short8 f0 = ldfrag(Rs,  0, k0, 512, lane);
          short8 f1 = ldfrag(Rs, 16, k0, 512, lane);
          short8 f3 = ldfrag(Rs, 48, k0, 512, lane);
          p0   = MFMA16(f3, f0, p0);      // (3,0)
          p1   = MFMA16(f3, f1, p1);      // (3,1)
          oacc = MFMA16(fs, f3, oacc);    // i-tile 3
        } else {
          short8 f1 = ldfrag(Rs, 16, k0, 512, lane);
          short8 f2 = ldfrag(Rs, 32, k0, 512, lane);
          short8 f3 = ldfrag(Rs, 48, k0, 512, lane);
          p0   = MFMA16(f3, f2, p0);      // (3,2)
          p1   = MFMA16(f3, f3, p1);      // (3,3)
          oacc = MFMA16(fs, f1, oacc);    // i-tile 1
        }
      }
      // epilogue: P~[i][j] = (j<i) ? gamma^i * acc : 0   (C-frag: col=j=lane&15, row=i=4*(lane>>4)+r)
      int tI[3], tJ[3], nt;
      if      (w == 0){ tI[0]=0; tJ[0]=0; tI[1]=1; tJ[1]=0; tI[2]=1; tJ[2]=1; nt = 3; }
      else if (w == 1){ tI[0]=2; tJ[0]=0; tI[1]=2; tJ[1]=1; tI[2]=2; tJ[2]=2; nt = 3; }
      else if (w == 2){ tI[0]=3; tJ[0]=0; tI[1]=3; tJ[1]=1; tI[2]=0; tJ[2]=0; nt = 2; }
      else            { tI[0]=3; tJ[0]=2; tI[1]=3; tJ[1]=3; tI[2]=0; tJ[2]=0; nt = 2; }
      f32x4 pacc[3] = {p0, p1, p2};
      for (int q = 0; q < nt; ++q){
        int j  = tJ[q] * 16 + (lane & 15);
        int i0 = tI[q] * 16 + ((lane >> 4) << 2);
        #pragma unroll
        for (int r = 0; r < 4; ++r){
          int i = i0 + r;
          float v = (j < i) ? pacc[q][r] * gpow[i] : 0.f;
          Ps[i * 64 + (j ^ ((i & 7) << 3))] = f2b(v);
        }
      }
    } else {
      // G4': state update S^T += VTs(A) x R-column-gather-from-GLOBAL(B), then *gamma^64
      int r0 = (w - 4) * 8;
      #pragma unroll
      for (int ks = 0; ks < 2; ++ks){
        short8 av = ldfrag(VTs[vb], 0, ks * 32, 64, lane);
        #pragma unroll
        for (int j = 0; j < 8; ++j){
          int n = (r0 + j) * 16 + (lane & 15);
          const unsigned short* col = Qc + (size_t)(ks * 32 + ((lane >> 4) << 3)) * Nn + n;
          short8 bn;
          #pragma unroll
          for (int e = 0; e < 8; ++e) bn[e] = (short)col[(size_t)e * Nn];
          st[j] = MFMA16(av, bn, st[j]);
        }
      }
      #pragma unroll
      for (int j = 0; j < 8; ++j)
        #pragma unroll
        for (int r = 0; r < 4; ++r) st[j][r] *= g64;
    }
    __syncthreads();

    // ================= Ph2: out store + staging for c+1 =================
    if (w >= 4){
      // SbT for chunk c+1 (st already updated+scaled = S_start(c+1))
      int r0 = (w - 4) * 8;
      #pragma unroll
      for (int j = 0; j < 8; ++j){
        int n  = (r0 + j) * 16 + (lane & 15);
        int dl = (lane >> 4) << 2;
        #pragma unroll
        for (int r = 0; r < 4; ++r){
          int d = dl + r;
          SbTs[d * 512 + (n ^ ((d & 7) << 3))] = f2b(st[j][r]);
        }
      }
    } else {
      // out = gamma^i * inter + intra
      const int itl = (w == 0) ? 0 : (w == 1) ? 2 : (w == 2) ? 3 : 1;
      float gi = gpow[itl * 16 + (lane & 15)];   // inter term scale gamma^i (col = i)
      #pragma unroll
      for (int r = 0; r < 4; ++r) oacc[r] *= gi;
      #pragma unroll
      for (int ks = 0; ks < 2; ++ks){
        short8 av = ldfrag(VTs[vb], 0, ks * 32, 64, lane);
        short8 bp = ldfrag(Ps, itl * 16, ks * 32, 64, lane);
        oacc = MFMA16(av, bp, oacc);   // OutT[d][i] += sum_j VT[d][j] * P~[i][j]
      }
      int ti = t0 + itl * 16 + (lane & 15);
      float* op = Out + (size_t)bh * Tn * Dn + (size_t)ti * Dn + d0 + ((lane >> 4) << 2);
      *reinterpret_cast<f32x4*>(op) = oacc;
    }
    // staging writes for chunk c+1 from prefetched registers (all waves; Rs dead)
    if (pf){
      #pragma unroll
      for (int i = 0; i < 4; ++i){
        int dt = (((tid >> 6) + 8 * i) << 1);
        stage_Rs(Rs, ra[i], rb[i], dt, n0_);
      }
      int dp = (tid & 7) << 1;
      float sc = gpinv[dtv_];
      VTs[vb ^ 1][ dp      * 64 + (dtv_ ^ (( dp      & 7) << 3))] = f2b(va0 * sc);
      VTs[vb ^ 1][(dp + 1) * 64 + (dtv_ ^ (((dp + 1) & 7) << 3))] = f2b(va1 * sc);
    }
    __syncthreads();
  }

  // ---- epilogue: final state ----
  if (w >= 4){
    int r0 = (w - 4) * 8;
    #pragma unroll
    for (int j = 0; j < 8; ++j){
      int n = (r0 + j) * 16 + (lane & 15);
      float* sp = Sfin + (size_t)bh * Nn * Dn + (size_t)n * Dn + d0 + ((lane >> 4) << 2);
      *reinterpret_cast<f32x4*>(sp) = st[j];
    }
  }
}

extern "C" void kernel_launch(void* const* d_in, const int* in_sizes, int n_in,
                              void* d_out, int out_size, void* d_ws, size_t ws_size,
                              hipStream_t stream){
  const float* Q      = (const float*)d_in[0];
  const float* V      = (const float*)d_in[1];
  const float* S_prev = (const float*)d_in[2];
  const float* freqs  = (const float*)d_in[3];
  const float* gamma  = (const float*)d_in[4];
  float* Out  = (float*)d_out;
  float* Sfin = Out + (size_t)BHn * Tn * Dn;
  unsigned short* QR = (unsigned short*)d_ws;   // 64 MB bf16 scratch

  rope_k<<<2048, 256, 0, stream>>>(Q, freqs, QR);
  lattn_main<<<256, 512, 0, stream>>>(QR, V, S_prev, gamma, Out, Sfin);
}